// Round 7
// baseline (283.180 us; speedup 1.0000x reference)
//
#include <hip/hip_runtime.h>

#define NPTS   50000
#define NEDGE  800000
#define NTILES 50000   // NEDGE/16
#define NSCAN  49      // ceil(NPTS/1024)

typedef short bf16x8 __attribute__((ext_vector_type(8)));
typedef float f32x4  __attribute__((ext_vector_type(4)));
typedef int   i32x4  __attribute__((ext_vector_type(4)));

// ws layout (bytes)
#define WS_SRCDST   0          // uint2[NEDGE]            6,400,000
#define WS_COUNTS   6400000    // int[NPTS]                 200,000
#define WS_CURSOR   6600000    // int[NPTS]                 200,000
#define WS_PART     6800000    // int[64]
#define WS_PPREF    6800256    // int[64]

// tanh-form GELU, |err| <= ~3e-4 vs exact erf gelu (threshold 0.171; measured absmax 0.03)
__device__ __forceinline__ float gelu_tanh(float v) {
    float v2 = v * v;
    float u2 = v * fmaf(v2, 0.0713548162726f, 1.5957691216057f);
    float e  = __expf(u2);
    float r  = __builtin_amdgcn_rcpf(e + 1.0f);
    return v - v * r;
}

__device__ __forceinline__ short f2bf(float f) {
    unsigned u = __builtin_bit_cast(unsigned, f);
    unsigned r = (u + 0x7FFFu + ((u >> 16) & 1u)) >> 16;
    return (short)r;
}

__device__ __forceinline__ int cvt_pk_bf16(float a, float b) {
    int r;
    asm("v_cvt_pk_bf16_f32 %0, %1, %2" : "=v"(r) : "v"(a), "v"(b));
    return r;
}

__device__ __forceinline__ int bperm(int addr, int v) {
    return __builtin_amdgcn_ds_bpermute(addr, v);
}
__device__ __forceinline__ int fbits(float v) { return __builtin_bit_cast(int, v); }
__device__ __forceinline__ float ibits(int v) { return __builtin_bit_cast(float, v); }

// ---------------- sort pipeline ----------------

__global__ void init_kernel(float* __restrict__ out, int* __restrict__ counts) {
    int i = blockIdx.x * blockDim.x + threadIdx.x;
    if (i < NPTS) counts[i] = 0;
    if (i < NEDGE) out[i < 16 * NPTS ? i : 0] = 0.0f;   // out has NPTS*16 = NEDGE floats
}

__global__ void hist_kernel(const int* __restrict__ ei, int* __restrict__ counts) {
    int e = blockIdx.x * blockDim.x + threadIdx.x;
    if (e >= NEDGE) return;
    int d = ei[NEDGE + e];
    d = min(max(d, 0), NPTS - 1);
    atomicAdd(&counts[d], 1);
}

__global__ __launch_bounds__(1024) void scan1_kernel(const int* __restrict__ counts,
                                                     int* __restrict__ partials) {
    __shared__ int ws_[16];
    int tid = threadIdx.x;
    int i = blockIdx.x * 1024 + tid;
    int v = (i < NPTS) ? counts[i] : 0;
#pragma unroll
    for (int k = 32; k >= 1; k >>= 1) v += __shfl_xor(v, k);
    if ((tid & 63) == 0) ws_[tid >> 6] = v;
    __syncthreads();
    if (tid == 0) {
        int s = 0;
#pragma unroll
        for (int w = 0; w < 16; ++w) s += ws_[w];
        partials[blockIdx.x] = s;
    }
}

__global__ void scan2_kernel(const int* __restrict__ partials, int* __restrict__ pprefix) {
    if (threadIdx.x == 0 && blockIdx.x == 0) {
        int run = 0;
        for (int b = 0; b < NSCAN; ++b) { pprefix[b] = run; run += partials[b]; }
    }
}

__global__ __launch_bounds__(1024) void scan3_kernel(const int* __restrict__ counts,
                                                     const int* __restrict__ pprefix,
                                                     int* __restrict__ cursor) {
    __shared__ int buf[2][1024];
    int tid = threadIdx.x;
    int i = blockIdx.x * 1024 + tid;
    int v = (i < NPTS) ? counts[i] : 0;
    buf[0][tid] = v;
    __syncthreads();
    int cur = 0;
#pragma unroll
    for (int off = 1; off < 1024; off <<= 1) {
        int t = buf[cur][tid] + (tid >= off ? buf[cur][tid - off] : 0);
        buf[cur ^ 1][tid] = t;
        cur ^= 1;
        __syncthreads();
    }
    if (i < NPTS) cursor[i] = buf[cur][tid] - v + pprefix[blockIdx.x];
}

__global__ void scatter_kernel(const int* __restrict__ ei, int* __restrict__ cursor,
                               unsigned long long* __restrict__ srcdst) {
    int e = blockIdx.x * blockDim.x + threadIdx.x;
    if (e >= NEDGE) return;
    int s = ei[e];
    int d = ei[NEDGE + e];
    s = min(max(s, 0), NPTS - 1);
    d = min(max(d, 0), NPTS - 1);
    int p = atomicAdd(&cursor[d], 1);
    unsigned long long pk = (unsigned long long)(unsigned)s |
                            ((unsigned long long)(unsigned)d << 32);
    __hip_atomic_store(&srcdst[p], pk, __ATOMIC_RELAXED, __HIP_MEMORY_SCOPE_AGENT);
}

// ---------------- main MFMA kernel (r5 structure + sorted input + segmented reduce) ----------------

__global__ __launch_bounds__(512, 4) void edge_mfma_kernel(
    const float* __restrict__ x,          // [NPTS*16]
    const float* __restrict__ pos,        // [NPTS*3]
    const uint2* __restrict__ srcdst,     // [NEDGE] dst-sorted {src,dst}
    const float* __restrict__ W1,
    const float* __restrict__ b1,
    const float* __restrict__ Wh,
    const float* __restrict__ bh,
    const float* __restrict__ Wo,
    const float* __restrict__ bo,
    float* __restrict__ out)              // [NPTS*16]
{
    __shared__ bf16x8 WoF[32][64];
    __shared__ bf16x8 WhF[8][64];
    __shared__ bf16x8 W1F[4][64];
    __shared__ bf16x8 BOF[64];
    __shared__ float  bhs[64];

    const int tid = threadIdx.x;

#pragma unroll
    for (int p = 0; p < 4; ++p) {
        int e_id = p * 512 + tid;
        int s  = e_id >> 6;
        int l  = e_id & 63;
        int er_ = l & 15, g = l >> 4;
        int i  = s >> 1, kt = s & 1;
        int n  = i * 16 + er_;
        int kb = kt * 32 + g * 8;
        bf16x8 f;
#pragma unroll
        for (int j = 0; j < 8; ++j)
            f[j] = f2bf(Wo[(kb + j) * 256 + n]);
        WoF[s][l] = f;
    }
    {
        int s  = tid >> 6;
        int l  = tid & 63;
        int er_ = l & 15, g = l >> 4;
        int m  = s >> 1, kt = s & 1;
        int n  = m * 16 + er_;
        int kb = kt * 32 + g * 8;
        bf16x8 f;
#pragma unroll
        for (int j = 0; j < 8; ++j)
            f[j] = f2bf(Wh[(kb + j) * 64 + n]);
        WhF[s][l] = f;
    }
    if (tid < 256) {
        int m  = tid >> 6;
        int l  = tid & 63;
        int er_ = l & 15, g = l >> 4;
        int n  = m * 16 + er_;
        bf16x8 f;
#pragma unroll
        for (int j = 0; j < 8; ++j) {
            int k = g * 8 + j;
            float v = (k < 6) ? W1[k * 64 + n] : (k == 6 ? b1[n] : 0.0f);
            f[j] = f2bf(v);
        }
        W1F[m][l] = f;
    }
    if (tid < 64) {
        int er_ = tid & 15, g = tid >> 4;
        bf16x8 f;
#pragma unroll
        for (int j = 0; j < 8; ++j) {
            int i = g * 8 + j;
            f[j] = (g < 2) ? f2bf(bo[i * 16 + er_]) : (short)0;
        }
        BOF[tid] = f;
        bhs[tid] = bh[tid];
    }
    __syncthreads();

    const int wave = tid >> 6;
    const int lane = tid & 63;
    const int grp  = lane >> 4;
    const int er   = lane & 15;

    const int addrH0 = (er + (grp & 1) * 32) * 4;
    const int addrH1 = addrH0 + 64;
    const bool selHi = (grp >= 2);
    int addrT[4], addrD[4];
#pragma unroll
    for (int r = 0; r < 4; ++r) {
        addrT[r] = ((er >> 2) * 16 + grp * 4 + r) * 4;
        addrD[r] = (grp * 4 + r) * 4;
    }
    const int selT = er & 3;
    // segmented-scan neighbor addresses (within-wave byte addrs)
    int addrS[4];
#pragma unroll
    for (int k = 0; k < 4; ++k) {
        int step = 1 << k;
        addrS[k] = (grp * 16 + min(er + step, 15)) * 4;
    }
    const int addrP = (grp * 16 + max(er - 1, 0)) * 4;

    const bf16x8* wof = &WoF[0][lane];
    const bf16x8* whf = &WhF[0][lane];
    const bf16x8* w1f = &W1F[0][lane];
    const bf16x8  bofr = BOF[lane];
    const f32x4 zero = {0.f, 0.f, 0.f, 0.f};

    const int tbase = blockIdx.x * 32 + wave * 4;

    bf16x8 apeT[4];
    int sT[4], dT[4];
#pragma unroll
    for (int tt = 0; tt < 4; ++tt) {
        int gt = tbase + tt; if (gt >= NTILES) gt = NTILES - 1;
        int eb = gt << 4;
        uint2 sd = srcdst[eb + er];
        int s = min((int)sd.x, NPTS - 1);
        int d = min((int)sd.y, NPTS - 1);
        sT[tt] = s; dT[tt] = d;
        float p0 = pos[s * 3 + 0], p1 = pos[s * 3 + 1], p2 = pos[s * 3 + 2];
        float p3 = pos[d * 3 + 0], p4 = pos[d * 3 + 1], p5 = pos[d * 3 + 2];
        const bool g0 = (grp == 0);
        bf16x8 ap;
        ap[0] = g0 ? f2bf(p0) : (short)0;
        ap[1] = g0 ? f2bf(p1) : (short)0;
        ap[2] = g0 ? f2bf(p2) : (short)0;
        ap[3] = g0 ? f2bf(p3) : (short)0;
        ap[4] = g0 ? f2bf(p4) : (short)0;
        ap[5] = g0 ? f2bf(p5) : (short)0;
        ap[6] = g0 ? (short)0x3F80 : (short)0;
        ap[7] = 0;
        apeT[tt] = ap;
    }

#pragma unroll
    for (int pp = 0; pp < 2; ++pp) {
        __syncthreads();
        const int t0 = 2 * pp;

        float xr[2][16];
#pragma unroll
        for (int q = 0; q < 2; ++q) {
            const float4* xp = reinterpret_cast<const float4*>(x + (size_t)sT[t0 + q] * 16);
            float4 a = xp[0], b = xp[1], c = xp[2], dd = xp[3];
            xr[q][0]=a.x;  xr[q][1]=a.y;  xr[q][2]=a.z;  xr[q][3]=a.w;
            xr[q][4]=b.x;  xr[q][5]=b.y;  xr[q][6]=b.z;  xr[q][7]=b.w;
            xr[q][8]=c.x;  xr[q][9]=c.y;  xr[q][10]=c.z; xr[q][11]=c.w;
            xr[q][12]=dd.x; xr[q][13]=dd.y; xr[q][14]=dd.z; xr[q][15]=dd.w;
        }

        float g1[2][4][4];
#pragma unroll
        for (int q = 0; q < 2; ++q)
#pragma unroll
            for (int m = 0; m < 4; ++m) {
                f32x4 c = __builtin_amdgcn_mfma_f32_16x16x32_bf16(w1f[m * 64], apeT[t0 + q], zero, 0, 0, 0);
#pragma unroll
                for (int r = 0; r < 4; ++r) g1[q][m][r] = gelu_tanh(c[r]);
            }

        bf16x8 B2[2][2];
#pragma unroll
        for (int q = 0; q < 2; ++q)
#pragma unroll
            for (int kt = 0; kt < 2; ++kt) {
                int pk0[2], pk1[2];
#pragma unroll
                for (int rp = 0; rp < 2; ++rp) {
                    pk0[rp] = cvt_pk_bf16(g1[q][2 * kt + 0][2 * rp], g1[q][2 * kt + 0][2 * rp + 1]);
                    pk1[rp] = cvt_pk_bf16(g1[q][2 * kt + 1][2 * rp], g1[q][2 * kt + 1][2 * rp + 1]);
                }
                i32x4 w;
#pragma unroll
                for (int h = 0; h < 2; ++h) {
                    int ah = h ? addrH1 : addrH0;
#pragma unroll
                    for (int rp = 0; rp < 2; ++rp) {
                        int vA = bperm(ah, pk0[rp]);
                        int vB = bperm(ah, pk1[rp]);
                        w[h * 2 + rp] = selHi ? vB : vA;
                    }
                }
                B2[q][kt] = __builtin_bit_cast(bf16x8, w);
            }

        float g2[2][4][4];
#pragma unroll
        for (int q = 0; q < 2; ++q)
#pragma unroll
            for (int m = 0; m < 4; ++m) {
                f32x4 c = __builtin_amdgcn_mfma_f32_16x16x32_bf16(whf[(2 * m + 0) * 64], B2[q][0], zero, 0, 0, 0);
                c = __builtin_amdgcn_mfma_f32_16x16x32_bf16(whf[(2 * m + 1) * 64], B2[q][1], c, 0, 0, 0);
                float4 b4 = *reinterpret_cast<const float4*>(&bhs[m * 16 + grp * 4]);
                float bb[4] = {b4.x, b4.y, b4.z, b4.w};
#pragma unroll
                for (int r = 0; r < 4; ++r) g2[q][m][r] = gelu_tanh(c[r] + bb[r]);
            }

        bf16x8 B3[2][2];
#pragma unroll
        for (int q = 0; q < 2; ++q)
#pragma unroll
            for (int kt = 0; kt < 2; ++kt) {
                int pk0[2], pk1[2];
#pragma unroll
                for (int rp = 0; rp < 2; ++rp) {
                    pk0[rp] = cvt_pk_bf16(g2[q][2 * kt + 0][2 * rp], g2[q][2 * kt + 0][2 * rp + 1]);
                    pk1[rp] = cvt_pk_bf16(g2[q][2 * kt + 1][2 * rp], g2[q][2 * kt + 1][2 * rp + 1]);
                }
                i32x4 w;
#pragma unroll
                for (int h = 0; h < 2; ++h) {
                    int ah = h ? addrH1 : addrH0;
#pragma unroll
                    for (int rp = 0; rp < 2; ++rp) {
                        int vA = bperm(ah, pk0[rp]);
                        int vB = bperm(ah, pk1[rp]);
                        w[h * 2 + rp] = selHi ? vB : vA;
                    }
                }
                B3[q][kt] = __builtin_bit_cast(bf16x8, w);
            }

        f32x4 msg[2];
#pragma unroll
        for (int q = 0; q < 2; ++q) {
            bf16x8 xb;
#pragma unroll
            for (int j = 0; j < 8; ++j) {
                float v = (grp == 0) ? xr[q][j] : ((grp == 1) ? xr[q][j + 8] : 0.0f);
                xb[j] = (grp < 2) ? f2bf(v) : (short)0;
            }
            msg[q] = __builtin_amdgcn_mfma_f32_16x16x32_bf16(bofr, xb, zero, 0, 0, 0);
        }

#pragma unroll
        for (int i = 0; i < 16; ++i)
#pragma unroll
            for (int q = 0; q < 2; ++q) {
                f32x4 c = __builtin_amdgcn_mfma_f32_16x16x32_bf16(wof[(2 * i + 0) * 64], B3[q][0], zero, 0, 0, 0);
                c = __builtin_amdgcn_mfma_f32_16x16x32_bf16(wof[(2 * i + 1) * 64], B3[q][1], c, 0, 0, 0);
#pragma unroll
                for (int r = 0; r < 4; ++r)
                    msg[q][r] = fmaf(xr[q][i], c[r], msg[q][r]);
            }

        // ---- segmented backward scan over er (dst-sorted => monotone keys per tile) ----
        // after scan, edge er holds sum over [er .. end-of-run]; head edges carry run totals
#pragma unroll
        for (int q = 0; q < 2; ++q) {
            const int gt = tbase + t0 + q;
            const bool ok = (gt < NTILES);
            const int dcur = dT[t0 + q];
            int dn[4];
#pragma unroll
            for (int k = 0; k < 4; ++k) dn[k] = bperm(addrS[k], dcur);
            const int dprev = bperm(addrP, dcur);
            const int headf = (er == 0 || dprev != dcur) ? 1 : 0;
#pragma unroll
            for (int k = 0; k < 4; ++k) {
                const int step = 1 << k;
                const bool c = (er + step < 16) && (dn[k] == dcur);
#pragma unroll
                for (int r = 0; r < 4; ++r) {
                    int o = bperm(addrS[k], fbits(msg[q][r]));
                    msg[q][r] += c ? ibits(o) : 0.0f;
                }
            }

            // ---- transpose scanned sums -> line-packed layout; atomic only at run heads ----
#pragma unroll
            for (int rd = 0; rd < 4; ++rd) {
                int u0 = bperm(addrT[rd], fbits(msg[q][0]));
                int u1 = bperm(addrT[rd], fbits(msg[q][1]));
                int u2 = bperm(addrT[rd], fbits(msg[q][2]));
                int u3 = bperm(addrT[rd], fbits(msg[q][3]));
                int v  = (selT == 0) ? u0 : (selT == 1) ? u1 : (selT == 2) ? u2 : u3;
                int dv = bperm(addrD[rd], dcur);
                int hf = bperm(addrD[rd], headf);
                if (ok && hf) atomicAdd(out + (size_t)dv * 16 + er, ibits(v));
            }
        }
    }
}

extern "C" void kernel_launch(void* const* d_in, const int* in_sizes, int n_in,
                              void* d_out, int out_size, void* d_ws, size_t ws_size,
                              hipStream_t stream) {
    const float* x   = (const float*)d_in[0];
    const float* pos = (const float*)d_in[1];
    const int*   ei  = (const int*)d_in[2];
    const float* W1  = (const float*)d_in[3];
    const float* b1  = (const float*)d_in[4];
    const float* Wh  = (const float*)d_in[5];
    const float* bh  = (const float*)d_in[6];
    const float* Wo  = (const float*)d_in[7];
    const float* bo  = (const float*)d_in[8];
    float* out = (float*)d_out;

    char* wsb = (char*)d_ws;
    unsigned long long* srcdst = (unsigned long long*)(wsb + WS_SRCDST);
    int* counts  = (int*)(wsb + WS_COUNTS);
    int* cursor  = (int*)(wsb + WS_CURSOR);
    int* partials= (int*)(wsb + WS_PART);
    int* pprefix = (int*)(wsb + WS_PPREF);

    init_kernel<<<(NEDGE + 255) / 256, 256, 0, stream>>>(out, counts);
    hist_kernel<<<(NEDGE + 255) / 256, 256, 0, stream>>>(ei, counts);
    scan1_kernel<<<NSCAN, 1024, 0, stream>>>(counts, partials);
    scan2_kernel<<<1, 64, 0, stream>>>(partials, pprefix);
    scan3_kernel<<<NSCAN, 1024, 0, stream>>>(counts, pprefix, cursor);
    scatter_kernel<<<(NEDGE + 255) / 256, 256, 0, stream>>>(ei, cursor, srcdst);

    const int nblocks = (NTILES + 31) / 32;
    edge_mfma_kernel<<<nblocks, 512, 0, stream>>>(
        x, pos, (const uint2*)srcdst, W1, b1, Wh, bh, Wo, bo, out);
}

// Round 8
// 169.979 us; speedup vs baseline: 1.6660x; 1.6660x over previous
//
#include <hip/hip_runtime.h>

#define NPTS   50000
#define NEDGE  800000
#define NTILES 50000   // NEDGE/16
#define NPAIRS 25000   // NTILES/2
#define NBLK   768     // persistent: 3 blocks/CU * 256 CU
#define TOTW   (NBLK * 8)

typedef short  bf16x8 __attribute__((ext_vector_type(8)));
typedef float  f32x4  __attribute__((ext_vector_type(4)));
typedef int    i32x4  __attribute__((ext_vector_type(4)));
typedef unsigned short u16x8 __attribute__((ext_vector_type(8)));

// tanh-form GELU, |err| <= ~3e-4 vs exact erf gelu (threshold 0.171; measured absmax 0.03)
__device__ __forceinline__ float gelu_tanh(float v) {
    float v2 = v * v;
    float u2 = v * fmaf(v2, 0.0713548162726f, 1.5957691216057f);
    float e  = __expf(u2);
    float r  = __builtin_amdgcn_rcpf(e + 1.0f);
    return v - v * r;
}

__device__ __forceinline__ short f2bf(float f) {
    unsigned u = __builtin_bit_cast(unsigned, f);
    unsigned r = (u + 0x7FFFu + ((u >> 16) & 1u)) >> 16;
    return (short)r;
}
__device__ __forceinline__ float bf2f(unsigned short h) {
    return __builtin_bit_cast(float, (unsigned)h << 16);
}

__device__ __forceinline__ int cvt_pk_bf16(float a, float b) {
    int r;
    asm("v_cvt_pk_bf16_f32 %0, %1, %2" : "=v"(r) : "v"(a), "v"(b));
    return r;
}

__device__ __forceinline__ int bperm(int addr, int v) {
    return __builtin_amdgcn_ds_bpermute(addr, v);
}
__device__ __forceinline__ int fbits(float v) { return __builtin_bit_cast(int, v); }
__device__ __forceinline__ float ibits(int v) { return __builtin_bit_cast(float, v); }

__global__ void zero_out_kernel(float* __restrict__ out, int n) {
    int i = blockIdx.x * blockDim.x + threadIdx.x;
    if (i < n) out[i] = 0.0f;
}

// x (f32) -> bf16 table in workspace: halves gather bytes + halves L2 footprint
__global__ void xcopy_kernel(const float* __restrict__ x, unsigned short* __restrict__ xbf) {
    int i = blockIdx.x * 256 + threadIdx.x;   // one float4 per thread
    if (i >= (NPTS * 16) / 4) return;
    float4 v = reinterpret_cast<const float4*>(x)[i];
    ushort4 o;
    o.x = (unsigned short)f2bf(v.x);
    o.y = (unsigned short)f2bf(v.y);
    o.z = (unsigned short)f2bf(v.z);
    o.w = (unsigned short)f2bf(v.w);
    reinterpret_cast<ushort4*>(xbf)[i] = o;
}

// Transposed-operand MFMA + 2-tile pipeline, persistent blocks (grid-stride over pairs).
__global__ __launch_bounds__(512, 4) void edge_mfma_kernel(
    const unsigned short* __restrict__ xbf,  // [NPTS*16] bf16
    const float* __restrict__ pos,           // [NPTS*3]
    const int*   __restrict__ ei,            // [2*NEDGE]
    const float* __restrict__ W1,
    const float* __restrict__ b1,
    const float* __restrict__ Wh,
    const float* __restrict__ bh,
    const float* __restrict__ Wo,
    const float* __restrict__ bo,
    float* __restrict__ out)                 // [NPTS*16]
{
    __shared__ bf16x8 WoF[32][64];
    __shared__ bf16x8 WhF[8][64];
    __shared__ bf16x8 W1F[4][64];
    __shared__ bf16x8 BOF[64];
    __shared__ float  bhs[64];

    const int tid = threadIdx.x;

    // ---- stage weight fragments (once per persistent block) ----
#pragma unroll
    for (int p = 0; p < 4; ++p) {
        int e_id = p * 512 + tid;
        int s  = e_id >> 6;
        int l  = e_id & 63;
        int er_ = l & 15, g = l >> 4;
        int i  = s >> 1, kt = s & 1;
        int n  = i * 16 + er_;
        int kb = kt * 32 + g * 8;
        bf16x8 f;
#pragma unroll
        for (int j = 0; j < 8; ++j)
            f[j] = f2bf(Wo[(kb + j) * 256 + n]);
        WoF[s][l] = f;
    }
    {
        int s  = tid >> 6;
        int l  = tid & 63;
        int er_ = l & 15, g = l >> 4;
        int m  = s >> 1, kt = s & 1;
        int n  = m * 16 + er_;
        int kb = kt * 32 + g * 8;
        bf16x8 f;
#pragma unroll
        for (int j = 0; j < 8; ++j)
            f[j] = f2bf(Wh[(kb + j) * 64 + n]);
        WhF[s][l] = f;
    }
    if (tid < 256) {
        int m  = tid >> 6;
        int l  = tid & 63;
        int er_ = l & 15, g = l >> 4;
        int n  = m * 16 + er_;
        bf16x8 f;
#pragma unroll
        for (int j = 0; j < 8; ++j) {
            int k = g * 8 + j;
            float v = (k < 6) ? W1[k * 64 + n] : (k == 6 ? b1[n] : 0.0f);
            f[j] = f2bf(v);
        }
        W1F[m][l] = f;
    }
    if (tid < 64) {
        int er_ = tid & 15, g = tid >> 4;
        bf16x8 f;
#pragma unroll
        for (int j = 0; j < 8; ++j) {
            int i = g * 8 + j;
            f[j] = (g < 2) ? f2bf(bo[i * 16 + er_]) : (short)0;
        }
        BOF[tid] = f;
        bhs[tid] = bh[tid];
    }
    __syncthreads();

    const int wave = tid >> 6;
    const int lane = tid & 63;
    const int grp  = lane >> 4;
    const int er   = lane & 15;

    const int addrH0 = (er + (grp & 1) * 32) * 4;
    const int addrH1 = addrH0 + 64;
    const bool selHi = (grp >= 2);
    int addrT[4], addrD[4];
#pragma unroll
    for (int r = 0; r < 4; ++r) {
        addrT[r] = ((er >> 2) * 16 + grp * 4 + r) * 4;
        addrD[r] = (grp * 4 + r) * 4;
    }
    const int selT = er & 3;

    const bf16x8* wof = &WoF[0][lane];
    const bf16x8* whf = &WhF[0][lane];
    const bf16x8* w1f = &W1F[0][lane];
    const bf16x8  bofr = BOF[lane];
    const f32x4 zero = {0.f, 0.f, 0.f, 0.f};

    const int gwave = blockIdx.x * 8 + wave;   // 0..TOTW-1

#pragma unroll 1
    for (int pr = gwave; pr < NPAIRS; pr += TOTW) {
        // ---- per-pair loads: tiles 2*pr, 2*pr+1; lane's edge = er ----
        int sQ[2], dQ[2];
        bf16x8 apeQ[2];
        u16x8 xA[2], xB[2];
#pragma unroll
        for (int q = 0; q < 2; ++q) {
            const int eb = (2 * pr + q) << 4;
            int s = ei[eb + er];
            int d = ei[NEDGE + eb + er];
            s = min(max(s, 0), NPTS - 1);
            d = min(max(d, 0), NPTS - 1);
            sQ[q] = s; dQ[q] = d;

            // bf16 x row (32B = 2x 16B loads)
            const u16x8* xp = reinterpret_cast<const u16x8*>(xbf + (size_t)s * 16);
            xA[q] = xp[0];
            xB[q] = xp[1];

            float p0 = pos[s * 3 + 0], p1 = pos[s * 3 + 1], p2 = pos[s * 3 + 2];
            float p3 = pos[d * 3 + 0], p4 = pos[d * 3 + 1], p5 = pos[d * 3 + 2];
            const bool g0 = (grp == 0);
            bf16x8 ap;
            ap[0] = g0 ? f2bf(p0) : (short)0;
            ap[1] = g0 ? f2bf(p1) : (short)0;
            ap[2] = g0 ? f2bf(p2) : (short)0;
            ap[3] = g0 ? f2bf(p3) : (short)0;
            ap[4] = g0 ? f2bf(p4) : (short)0;
            ap[5] = g0 ? f2bf(p5) : (short)0;
            ap[6] = g0 ? (short)0x3F80 : (short)0;   // bf16(1.0) -> b1 rides k==6
            ap[7] = 0;
            apeQ[q] = ap;
        }

        // ---- layer 1 ----
        float g1[2][4][4];
#pragma unroll
        for (int q = 0; q < 2; ++q)
#pragma unroll
            for (int m = 0; m < 4; ++m) {
                f32x4 c = __builtin_amdgcn_mfma_f32_16x16x32_bf16(w1f[m * 64], apeQ[q], zero, 0, 0, 0);
#pragma unroll
                for (int r = 0; r < 4; ++r) g1[q][m][r] = gelu_tanh(c[r]);
            }

        // ---- B2 frags: pack-then-permute ----
        bf16x8 B2[2][2];
#pragma unroll
        for (int q = 0; q < 2; ++q)
#pragma unroll
            for (int kt = 0; kt < 2; ++kt) {
                int pk0[2], pk1[2];
#pragma unroll
                for (int rp = 0; rp < 2; ++rp) {
                    pk0[rp] = cvt_pk_bf16(g1[q][2 * kt + 0][2 * rp], g1[q][2 * kt + 0][2 * rp + 1]);
                    pk1[rp] = cvt_pk_bf16(g1[q][2 * kt + 1][2 * rp], g1[q][2 * kt + 1][2 * rp + 1]);
                }
                i32x4 w;
#pragma unroll
                for (int h = 0; h < 2; ++h) {
                    int ah = h ? addrH1 : addrH0;
#pragma unroll
                    for (int rp = 0; rp < 2; ++rp) {
                        int vA = bperm(ah, pk0[rp]);
                        int vB = bperm(ah, pk1[rp]);
                        w[h * 2 + rp] = selHi ? vB : vA;
                    }
                }
                B2[q][kt] = __builtin_bit_cast(bf16x8, w);
            }

        // ---- layer 2 ----
        float g2[2][4][4];
#pragma unroll
        for (int q = 0; q < 2; ++q)
#pragma unroll
            for (int m = 0; m < 4; ++m) {
                f32x4 c = __builtin_amdgcn_mfma_f32_16x16x32_bf16(whf[(2 * m + 0) * 64], B2[q][0], zero, 0, 0, 0);
                c = __builtin_amdgcn_mfma_f32_16x16x32_bf16(whf[(2 * m + 1) * 64], B2[q][1], c, 0, 0, 0);
                float4 b4 = *reinterpret_cast<const float4*>(&bhs[m * 16 + grp * 4]);
                float bb[4] = {b4.x, b4.y, b4.z, b4.w};
#pragma unroll
                for (int r = 0; r < 4; ++r) g2[q][m][r] = gelu_tanh(c[r] + bb[r]);
            }

        // ---- B3 frags ----
        bf16x8 B3[2][2];
#pragma unroll
        for (int q = 0; q < 2; ++q)
#pragma unroll
            for (int kt = 0; kt < 2; ++kt) {
                int pk0[2], pk1[2];
#pragma unroll
                for (int rp = 0; rp < 2; ++rp) {
                    pk0[rp] = cvt_pk_bf16(g2[q][2 * kt + 0][2 * rp], g2[q][2 * kt + 0][2 * rp + 1]);
                    pk1[rp] = cvt_pk_bf16(g2[q][2 * kt + 1][2 * rp], g2[q][2 * kt + 1][2 * rp + 1]);
                }
                i32x4 w;
#pragma unroll
                for (int h = 0; h < 2; ++h) {
                    int ah = h ? addrH1 : addrH0;
#pragma unroll
                    for (int rp = 0; rp < 2; ++rp) {
                        int vA = bperm(ah, pk0[rp]);
                        int vB = bperm(ah, pk1[rp]);
                        w[h * 2 + rp] = selHi ? vB : vA;
                    }
                }
                B3[q][kt] = __builtin_bit_cast(bf16x8, w);
            }

        // ---- bo contribution: msg = BOF @ X^T (x already bf16) ----
        f32x4 msg[2];
#pragma unroll
        for (int q = 0; q < 2; ++q) {
            bf16x8 xb;
#pragma unroll
            for (int j = 0; j < 8; ++j) {
                short v = (grp == 0) ? (short)xA[q][j] : ((grp == 1) ? (short)xB[q][j] : (short)0);
                xb[j] = v;
            }
            msg[q] = __builtin_amdgcn_mfma_f32_16x16x32_bf16(bofr, xb, zero, 0, 0, 0);
        }

        // ---- layer 3 + einsum ----
#pragma unroll
        for (int i = 0; i < 16; ++i)
#pragma unroll
            for (int q = 0; q < 2; ++q) {
                f32x4 c = __builtin_amdgcn_mfma_f32_16x16x32_bf16(wof[(2 * i + 0) * 64], B3[q][0], zero, 0, 0, 0);
                c = __builtin_amdgcn_mfma_f32_16x16x32_bf16(wof[(2 * i + 1) * 64], B3[q][1], c, 0, 0, 0);
                float xf = bf2f(i < 8 ? xA[q][i] : xB[q][i - 8]);
#pragma unroll
                for (int r = 0; r < 4; ++r)
                    msg[q][r] = fmaf(xf, c[r], msg[q][r]);
            }

        // ---- transpose msg across lanes -> line-packed atomics (64B/edge) ----
#pragma unroll
        for (int q = 0; q < 2; ++q) {
#pragma unroll
            for (int rd = 0; rd < 4; ++rd) {
                int u0 = bperm(addrT[rd], fbits(msg[q][0]));
                int u1 = bperm(addrT[rd], fbits(msg[q][1]));
                int u2 = bperm(addrT[rd], fbits(msg[q][2]));
                int u3 = bperm(addrT[rd], fbits(msg[q][3]));
                int v  = (selT == 0) ? u0 : (selT == 1) ? u1 : (selT == 2) ? u2 : u3;
                int dv = bperm(addrD[rd], dQ[q]);
                atomicAdd(out + (size_t)dv * 16 + er, ibits(v));
            }
        }
    }
}

extern "C" void kernel_launch(void* const* d_in, const int* in_sizes, int n_in,
                              void* d_out, int out_size, void* d_ws, size_t ws_size,
                              hipStream_t stream) {
    const float* x   = (const float*)d_in[0];
    const float* pos = (const float*)d_in[1];
    const int*   ei  = (const int*)d_in[2];
    const float* W1  = (const float*)d_in[3];
    const float* b1  = (const float*)d_in[4];
    const float* Wh  = (const float*)d_in[5];
    const float* bh  = (const float*)d_in[6];
    const float* Wo  = (const float*)d_in[7];
    const float* bo  = (const float*)d_in[8];
    float* out = (float*)d_out;
    unsigned short* xbf = (unsigned short*)d_ws;   // 1.6 MB bf16 x-table

    zero_out_kernel<<<(out_size + 255) / 256, 256, 0, stream>>>(out, out_size);
    xcopy_kernel<<<((NPTS * 16 / 4) + 255) / 256, 256, 0, stream>>>(x, xbf);
    edge_mfma_kernel<<<NBLK, 512, 0, stream>>>(
        xbf, pos, ei, W1, b1, Wh, bh, Wo, bo, out);
}